// Round 10
// baseline (252.132 us; speedup 1.0000x reference)
//
#include <hip/hip_runtime.h>

#define BDIM 256

constexpr int K      = 32;
constexpr int L1     = 1024;
constexpr int L2C    = 15;
constexpr int L3C    = 32;
constexpr int COUNT  = 9;
constexpr int NF     = 22528;
constexpr int W1COLS = COUNT * (L2C + 1); // 144
constexpr int W2COLS = COUNT * L3C;       // 288

__device__ __forceinline__ float clip01(float x) {
    return fminf(fmaxf(x, 0.0f), 1.0f);
}

// padded LDS index: stride-17 per 16 elements (17 coprime 32 -> scalar
// access 2 lanes/bank = conflict-free per wave)
__device__ __forceinline__ int PADI(int e) { return e + (e >> 4); }

// ---- fp32 -> uint8 (excess-128) per-row quantization of W_ft ----
// Lane owns 16 consecutive cols -> one uint4 (16 B) store per lane.
// Rebuilt every iteration (workspace re-poisoned; R1 proved memoization
// never survives).
__global__ __launch_bounds__(256) void quant_w_ft(const float* __restrict__ src,
                                                  unsigned char* __restrict__ dst,
                                                  float* __restrict__ scales,
                                                  int nrows) {
    const int wq   = threadIdx.x >> 6;          // wave in block
    const int lane = threadIdx.x & 63;
    const int row  = blockIdx.x * 4 + wq;
    if (row >= nrows) return;

    const float* s = src + (long)row * L1 + lane * 16;
    float4 v[4];
    v[0] = *(const float4*)(s);
    v[1] = *(const float4*)(s + 4);
    v[2] = *(const float4*)(s + 8);
    v[3] = *(const float4*)(s + 12);

    float m = 0.0f;
    #pragma unroll
    for (int i = 0; i < 4; ++i)
        m = fmaxf(m, fmaxf(fmaxf(fabsf(v[i].x), fabsf(v[i].y)),
                           fmaxf(fabsf(v[i].z), fabsf(v[i].w))));
    #pragma unroll
    for (int off = 32; off >= 1; off >>= 1)
        m = fmaxf(m, __shfl_xor(m, off));

    const float mm    = fmaxf(m, 1e-30f);
    const float scale = mm / 127.0f;
    const float inv   = 127.0f / mm;

    uint4 pk;
    unsigned* pw = (unsigned*)&pk;
    #pragma unroll
    for (int i = 0; i < 4; ++i) {
        int q0 = (int)rintf(v[i].x * inv) + 128;
        int q1 = (int)rintf(v[i].y * inv) + 128;
        int q2 = (int)rintf(v[i].z * inv) + 128;
        int q3 = (int)rintf(v[i].w * inv) + 128;
        q0 = max(0, min(255, q0)); q1 = max(0, min(255, q1));
        q2 = max(0, min(255, q2)); q3 = max(0, min(255, q3));
        pw[i] = (unsigned)q0 | ((unsigned)q1 << 8) |
                ((unsigned)q2 << 16) | ((unsigned)q3 << 24);
    }
    *(uint4*)(dst + (long)row * L1 + lane * 16) = pk;
    if (lane == 0) scales[row] = scale;
}

// ---- fused NNUE forward, uint8 table, full-row 16 B/lane gather ----
// R10: cross-round table shows a ~90 G cache-lines/s service ceiling hit
// by the 16-line wave-instr variants (fp32 R2, fp16 R3) while int8's
// 8-line instrs sit at 59 G. Restore 16-line instrs for int8 WITHOUT
// R5's k-split: waves 0/1 gather (wave=persp, 64 lanes x 16 B = one full
// 1 KB row per instr), full k=32/thread, no partial combine. LDS stores
// via stride-17 padding, 16 scalar ds_write_b32 (2 lanes/bank = free).
// Tail = R4's verified structure with PADI(e) indexing.
__global__ __launch_bounds__(BDIM) void nnue_fused_q(
    const float* __restrict__ us,
    const float* __restrict__ them,
    const int*   __restrict__ wi,
    const float* __restrict__ wv,
    const int*   __restrict__ bi,
    const float* __restrict__ bvv,
    const int*   __restrict__ lsi,
    const unsigned char* __restrict__ Wq,
    const float* __restrict__ scl,
    const float* __restrict__ b_ft,
    const float* __restrict__ W1,
    const float* __restrict__ b1,
    const float* __restrict__ W2,
    const float* __restrict__ b2,
    const float* __restrict__ W3,
    const float* __restrict__ b3,
    float* __restrict__ out)
{
    const int b = blockIdx.x;
    const int t = threadIdx.x;

    __shared__ int   s_idx[2 * K];
    __shared__ float s_val[2 * K];        // val * scale[row]
    __shared__ float s_wp[64 * 17];       // padded: e -> e + (e>>4)
    __shared__ float s_bp[64 * 17];
    __shared__ float s_red[4 * 16];
    __shared__ float s_v[2 * L2C];
    __shared__ float s_p2[L3C];
    __shared__ float s_l1f;

    // ---- stage sparse indices/values (scale folded into value) ----
    if (t < K) {
        const int ii = wi[b * K + t];
        s_idx[t] = ii;
        s_val[t] = wv[b * K + t] * scl[ii];
    } else if (t < 2 * K) {
        const int ii = bi[b * K + (t - K)];
        s_idx[t] = ii;
        s_val[t] = bvv[b * K + (t - K)] * scl[ii];
    }
    __syncthreads();

    // ---- feature transform: waves 0,1 only; 16 B/lane = full row/instr ----
    const int w    = t >> 6;
    const int lane = t & 63;
    if (w < 2) {
        const int persp = w;              // 0 = white, 1 = black
        const int c16   = lane * 16;      // 16 cols per lane
        const int*   idxs = s_idx + persp * K;
        const float* vals = s_val + persp * K;

        float acc[16];
        #pragma unroll
        for (int j = 0; j < 16; j += 4) {
            const float4 bf = *(const float4*)(b_ft + c16 + j);
            acc[j] = bf.x; acc[j + 1] = bf.y; acc[j + 2] = bf.z; acc[j + 3] = bf.w;
        }

        float sumvs = 0.0f;
        #pragma unroll 8
        for (int k = 0; k < K; ++k) {
            const float vs = vals[k];
            const uint4 q  = *(const uint4*)(Wq + ((long)idxs[k] << 10) + c16);
            sumvs += vs;
            acc[0]  = fmaf(vs, (float)( q.x        & 0xffu), acc[0]);
            acc[1]  = fmaf(vs, (float)((q.x >>  8) & 0xffu), acc[1]);
            acc[2]  = fmaf(vs, (float)((q.x >> 16) & 0xffu), acc[2]);
            acc[3]  = fmaf(vs, (float)( q.x >> 24        ), acc[3]);
            acc[4]  = fmaf(vs, (float)( q.y        & 0xffu), acc[4]);
            acc[5]  = fmaf(vs, (float)((q.y >>  8) & 0xffu), acc[5]);
            acc[6]  = fmaf(vs, (float)((q.y >> 16) & 0xffu), acc[6]);
            acc[7]  = fmaf(vs, (float)( q.y >> 24        ), acc[7]);
            acc[8]  = fmaf(vs, (float)( q.z        & 0xffu), acc[8]);
            acc[9]  = fmaf(vs, (float)((q.z >>  8) & 0xffu), acc[9]);
            acc[10] = fmaf(vs, (float)((q.z >> 16) & 0xffu), acc[10]);
            acc[11] = fmaf(vs, (float)( q.z >> 24        ), acc[11]);
            acc[12] = fmaf(vs, (float)( q.w        & 0xffu), acc[12]);
            acc[13] = fmaf(vs, (float)((q.w >>  8) & 0xffu), acc[13]);
            acc[14] = fmaf(vs, (float)((q.w >> 16) & 0xffu), acc[14]);
            acc[15] = fmaf(vs, (float)( q.w >> 24        ), acc[15]);
        }
        #pragma unroll
        for (int j = 0; j < 16; ++j) acc[j] = fmaf(sumvs, -128.0f, acc[j]);

        // stride-17 padded scalar stores (2 lanes/bank = free)
        float* dst = (persp == 0 ? s_wp : s_bp) + lane * 17;
        #pragma unroll
        for (int j = 0; j < 16; ++j) dst[j] = acc[j];
    }
    __syncthreads();

    const float u   = us[b];
    const float th  = them[b];
    const int   idx = lsi[b];
    const float cc  = 127.0f / 128.0f;

    // ---- layer 1 (R4 structure, padded indices) ----
    float p[16];
    #pragma unroll
    for (int j = 0; j < 16; ++j) p[j] = 0.0f;

    const float* W1sel = W1 + idx * (L2C + 1);
    const int e0 = t * 4;
    #pragma unroll
    for (int q = 0; q < 4; ++q) {
        const int e = e0 + q;
        float l0p;
        if (e < 512) {
            const float a0 = clip01(u * s_wp[PADI(e)]       + th * s_bp[PADI(e)]);
            const float a1 = clip01(u * s_wp[PADI(e + 512)] + th * s_bp[PADI(e + 512)]);
            l0p = a0 * a1;
        } else {
            const int   c   = e - 512;
            const float b0  = clip01(u * s_bp[PADI(c)] + th * s_wp[PADI(c)]);
            const float b1v = clip01(u * s_bp[PADI(e)] + th * s_wp[PADI(e)]);
            l0p = b0 * b1v;
        }
        l0p *= cc;
        const float* wrow = W1sel + e * W1COLS;
        #pragma unroll
        for (int j = 0; j < 16; ++j) p[j] = fmaf(l0p, wrow[j], p[j]);
    }

    const int lane2 = t & 63;
    const int wid   = t >> 6;
    #pragma unroll
    for (int j = 0; j < 16; ++j) {
        float v = p[j];
        v += __shfl_down(v, 32);
        v += __shfl_down(v, 16);
        v += __shfl_down(v, 8);
        v += __shfl_down(v, 4);
        v += __shfl_down(v, 2);
        v += __shfl_down(v, 1);
        if (lane2 == 0) s_red[wid * 16 + j] = v;
    }
    __syncthreads();

    if (t < 16) {
        float x1 = s_red[t] + s_red[16 + t] + s_red[32 + t] + s_red[48 + t]
                 + b1[idx * (L2C + 1) + t];
        if (t == 15) {
            s_l1f = x1;
        } else {
            float cx = clip01(x1);
            s_v[t]       = cx * cx * cc;
            s_v[L2C + t] = cx * cc;
        }
    }
    __syncthreads();

    if (t < L3C) {
        float acc2 = b2[idx * L3C + t];
        #pragma unroll
        for (int r = 0; r < 2 * L2C; ++r)
            acc2 = fmaf(s_v[r], W2[r * W2COLS + idx * L3C + t], acc2);
        s_p2[t] = clip01(acc2) * W3[t * COUNT + idx];
    }
    __syncthreads();

    if (t == 0) {
        float s = 0.0f;
        #pragma unroll
        for (int m = 0; m < L3C; ++m) s += s_p2[m];
        out[b] = s + b3[idx] + s_l1f;
    }
}

// ---- fp32 single-kernel fallback (ws too small) — verified 186 us ----
__global__ __launch_bounds__(BDIM) void nnue_fused_f(
    const float* __restrict__ us,
    const float* __restrict__ them,
    const int*   __restrict__ wi,
    const float* __restrict__ wv,
    const int*   __restrict__ bi,
    const float* __restrict__ bvv,
    const int*   __restrict__ lsi,
    const float* __restrict__ W_ft,
    const float* __restrict__ b_ft,
    const float* __restrict__ W1,
    const float* __restrict__ b1,
    const float* __restrict__ W2,
    const float* __restrict__ b2,
    const float* __restrict__ W3,
    const float* __restrict__ b3,
    float* __restrict__ out)
{
    const int b = blockIdx.x;
    const int t = threadIdx.x;

    __shared__ int   s_idx[2 * K];
    __shared__ float s_val[2 * K];
    __shared__ float s_l0[2 * L1];
    __shared__ float s_red[4 * 16];
    __shared__ float s_v[2 * L2C];
    __shared__ float s_p2[L3C];
    __shared__ float s_l1f;

    if (t < K)          { s_idx[t] = wi[b * K + t];        s_val[t] = wv[b * K + t]; }
    else if (t < 2 * K) { s_idx[t] = bi[b * K + (t - K)];  s_val[t] = bvv[b * K + (t - K)]; }
    __syncthreads();

    const int c4 = t * 4;
    float4 accW = *(const float4*)(b_ft + c4);
    float4 accB = accW;

    #pragma unroll 8
    for (int k = 0; k < K; ++k) {
        const float  vwk = s_val[k];
        const float  vbk = s_val[K + k];
        const float4 rw  = *(const float4*)(W_ft + ((long)s_idx[k]     << 10) + c4);
        const float4 rb  = *(const float4*)(W_ft + ((long)s_idx[K + k] << 10) + c4);
        accW.x = fmaf(vwk, rw.x, accW.x);
        accW.y = fmaf(vwk, rw.y, accW.y);
        accW.z = fmaf(vwk, rw.z, accW.z);
        accW.w = fmaf(vwk, rw.w, accW.w);
        accB.x = fmaf(vbk, rb.x, accB.x);
        accB.y = fmaf(vbk, rb.y, accB.y);
        accB.z = fmaf(vbk, rb.z, accB.z);
        accB.w = fmaf(vbk, rb.w, accB.w);
    }

    const float u  = us[b];
    const float th = them[b];
    float4 A, Bv;
    A.x  = clip01(u * accW.x + th * accB.x);
    A.y  = clip01(u * accW.y + th * accB.y);
    A.z  = clip01(u * accW.z + th * accB.z);
    A.w  = clip01(u * accW.w + th * accB.w);
    Bv.x = clip01(u * accB.x + th * accW.x);
    Bv.y = clip01(u * accB.y + th * accW.y);
    Bv.z = clip01(u * accB.z + th * accW.z);
    Bv.w = clip01(u * accB.w + th * accW.w);
    *(float4*)(s_l0 + c4)      = A;
    *(float4*)(s_l0 + L1 + c4) = Bv;
    __syncthreads();

    const int   idx = lsi[b];
    const float cc  = 127.0f / 128.0f;

    float p[16];
    #pragma unroll
    for (int j = 0; j < 16; ++j) p[j] = 0.0f;

    const float* W1sel = W1 + idx * (L2C + 1);
    #pragma unroll
    for (int q = 0; q < 4; ++q) {
        const int e = c4 + q;
        float l0p;
        if (e < 512) l0p = s_l0[e] * s_l0[e + 512];
        else         l0p = s_l0[e + 512] * s_l0[e + 1024];
        l0p *= cc;
        const float* wrow = W1sel + e * W1COLS;
        #pragma unroll
        for (int j = 0; j < 16; ++j) p[j] = fmaf(l0p, wrow[j], p[j]);
    }

    const int lane = t & 63;
    const int wid  = t >> 6;
    #pragma unroll
    for (int j = 0; j < 16; ++j) {
        float v = p[j];
        v += __shfl_down(v, 32);
        v += __shfl_down(v, 16);
        v += __shfl_down(v, 8);
        v += __shfl_down(v, 4);
        v += __shfl_down(v, 2);
        v += __shfl_down(v, 1);
        if (lane == 0) s_red[wid * 16 + j] = v;
    }
    __syncthreads();

    if (t < 16) {
        float x1 = s_red[t] + s_red[16 + t] + s_red[32 + t] + s_red[48 + t]
                 + b1[idx * (L2C + 1) + t];
        if (t == 15) {
            s_l1f = x1;
        } else {
            float cx = clip01(x1);
            s_v[t]       = cx * cx * cc;
            s_v[L2C + t] = cx * cc;
        }
    }
    __syncthreads();

    if (t < L3C) {
        float acc = b2[idx * L3C + t];
        #pragma unroll
        for (int r = 0; r < 2 * L2C; ++r)
            acc = fmaf(s_v[r], W2[r * W2COLS + idx * L3C + t], acc);
        s_p2[t] = clip01(acc) * W3[t * COUNT + idx];
    }
    __syncthreads();

    if (t == 0) {
        float s = 0.0f;
        #pragma unroll
        for (int m = 0; m < L3C; ++m) s += s_p2[m];
        out[b] = s + b3[idx] + s_l1f;
    }
}

extern "C" void kernel_launch(void* const* d_in, const int* in_sizes, int n_in,
                              void* d_out, int out_size, void* d_ws, size_t ws_size,
                              hipStream_t stream) {
    const float* us   = (const float*)d_in[0];
    const float* them = (const float*)d_in[1];
    const int*   wi   = (const int*)  d_in[2];
    const float* wv   = (const float*)d_in[3];
    const int*   bi   = (const int*)  d_in[4];
    const float* bv   = (const float*)d_in[5];
    const int*   lsi  = (const int*)  d_in[6];
    const float* W_ft = (const float*)d_in[7];
    const float* b_ft = (const float*)d_in[8];
    const float* W1   = (const float*)d_in[9];
    const float* b1   = (const float*)d_in[10];
    const float* W2   = (const float*)d_in[11];
    const float* b2   = (const float*)d_in[12];
    const float* W3   = (const float*)d_in[13];
    const float* b3   = (const float*)d_in[14];
    float*       out  = (float*)d_out;

    const int Bn = in_sizes[0]; // 4096 batch rows
    const size_t qTableBytes = (size_t)NF * L1;                  // 23.1 MB
    const size_t needed      = qTableBytes + (size_t)NF * sizeof(float);

    if (ws_size >= needed) {
        unsigned char* Wq  = (unsigned char*)d_ws;
        float*         scl = (float*)((char*)d_ws + qTableBytes);
        quant_w_ft<<<(NF + 3) / 4, 256, 0, stream>>>(W_ft, Wq, scl, NF);
        nnue_fused_q<<<Bn, BDIM, 0, stream>>>(us, them, wi, wv, bi, bv, lsi,
                                              Wq, scl, b_ft, W1, b1, W2, b2, W3, b3, out);
    } else {
        nnue_fused_f<<<Bn, BDIM, 0, stream>>>(us, them, wi, wv, bi, bv, lsi,
                                              W_ft, b_ft, W1, b1, W2, b2, W3, b3, out);
    }
}

// Round 11
// 234.222 us; speedup vs baseline: 1.0765x; 1.0765x over previous
//
#include <hip/hip_runtime.h>

#define BDIM 256

constexpr int K      = 32;
constexpr int L1     = 1024;
constexpr int L2C    = 15;
constexpr int L3C    = 32;
constexpr int COUNT  = 9;
constexpr int NF     = 22528;
constexpr int W1COLS = COUNT * (L2C + 1); // 144
constexpr int W2COLS = COUNT * L3C;       // 288

typedef __attribute__((ext_vector_type(4))) float f32x4;

__device__ __forceinline__ float clip01(float x) {
    return fminf(fmaxf(x, 0.0f), 1.0f);
}

// ---- fp32 -> uint8 (excess-128) per-row quantization of W_ft ----
// R11: exact R7 structure; single delta = nontemporal loads on the dead
// fp32 stream (92 MB read once/iter) so it doesn't churn L2/L3 and evict
// the int8 table that the gather re-reads ~12x. Lane owns 16 consecutive
// cols -> one uint4 (16 B) store.
__global__ __launch_bounds__(256) void quant_w_ft(const float* __restrict__ src,
                                                  unsigned char* __restrict__ dst,
                                                  float* __restrict__ scales,
                                                  int nrows) {
    const int wq   = threadIdx.x >> 6;          // wave in block
    const int lane = threadIdx.x & 63;
    const int row  = blockIdx.x * 4 + wq;
    if (row >= nrows) return;

    const f32x4* s = (const f32x4*)(src + (long)row * L1 + lane * 16);
    f32x4 v[4];
    v[0] = __builtin_nontemporal_load(s);
    v[1] = __builtin_nontemporal_load(s + 1);
    v[2] = __builtin_nontemporal_load(s + 2);
    v[3] = __builtin_nontemporal_load(s + 3);

    float m = 0.0f;
    #pragma unroll
    for (int i = 0; i < 4; ++i)
        m = fmaxf(m, fmaxf(fmaxf(fabsf(v[i].x), fabsf(v[i].y)),
                           fmaxf(fabsf(v[i].z), fabsf(v[i].w))));
    #pragma unroll
    for (int off = 32; off >= 1; off >>= 1)
        m = fmaxf(m, __shfl_xor(m, off));

    const float mm    = fmaxf(m, 1e-30f);
    const float scale = mm / 127.0f;
    const float inv   = 127.0f / mm;

    uint4 pk;
    unsigned* pw = (unsigned*)&pk;
    #pragma unroll
    for (int i = 0; i < 4; ++i) {
        int q0 = (int)rintf(v[i].x * inv) + 128;
        int q1 = (int)rintf(v[i].y * inv) + 128;
        int q2 = (int)rintf(v[i].z * inv) + 128;
        int q3 = (int)rintf(v[i].w * inv) + 128;
        q0 = max(0, min(255, q0)); q1 = max(0, min(255, q1));
        q2 = max(0, min(255, q2)); q3 = max(0, min(255, q3));
        pw[i] = (unsigned)q0 | ((unsigned)q1 << 8) |
                ((unsigned)q2 << 16) | ((unsigned)q3 << 24);
    }
    *(uint4*)(dst + (long)row * L1 + lane * 16) = pk;
    if (lane == 0) scales[row] = scale;
}

// ---- fused NNUE forward, uint8 table (exact R4/R7 verified structure) ----
// 71.2 us, verified twice (R4, R7). Six structural attacks (R5 instr count,
// R6 bank conflicts, R7 unpack, R8 2-row ILP, R9 unroll depth, R10 wave
// shape) all failed to beat it: the gather sits at the measured ~3.8 TB/s
// random-access service rate for 1 KB-contiguous rows (run-length-bound,
// fixed by the int8 row size).
__global__ __launch_bounds__(BDIM) void nnue_fused_q(
    const float* __restrict__ us,
    const float* __restrict__ them,
    const int*   __restrict__ wi,
    const float* __restrict__ wv,
    const int*   __restrict__ bi,
    const float* __restrict__ bvv,
    const int*   __restrict__ lsi,
    const unsigned char* __restrict__ Wq,
    const float* __restrict__ scl,
    const float* __restrict__ b_ft,
    const float* __restrict__ W1,
    const float* __restrict__ b1,
    const float* __restrict__ W2,
    const float* __restrict__ b2,
    const float* __restrict__ W3,
    const float* __restrict__ b3,
    float* __restrict__ out)
{
    const int b = blockIdx.x;
    const int t = threadIdx.x;

    __shared__ int   s_idx[2 * K];
    __shared__ float s_val[2 * K];   // val * scale[row]
    __shared__ float s_wp[L1];
    __shared__ float s_bp[L1];
    __shared__ float s_red[4 * 16];
    __shared__ float s_v[2 * L2C];
    __shared__ float s_p2[L3C];
    __shared__ float s_l1f;

    // ---- stage sparse indices/values (scale folded into value) ----
    if (t < K) {
        const int ii = wi[b * K + t];
        s_idx[t] = ii;
        s_val[t] = wv[b * K + t] * scl[ii];
    } else if (t < 2 * K) {
        const int ii = bi[b * K + (t - K)];
        s_idx[t] = ii;
        s_val[t] = bvv[b * K + (t - K)] * scl[ii];
    }
    __syncthreads();

    // ---- feature transform: 8 B per row access per lane ----
    const int   half = t >> 7;        // 0 = white, 1 = black
    const int   tc   = t & 127;
    const int   c8   = tc * 8;        // byte offset == col offset (1 B/col)
    const int*   idxs = s_idx + half * K;
    const float* vals = s_val + half * K;

    float acc[8];
    {
        const float4 bf0 = *(const float4*)(b_ft + c8);
        const float4 bf1 = *(const float4*)(b_ft + c8 + 4);
        acc[0] = bf0.x; acc[1] = bf0.y; acc[2] = bf0.z; acc[3] = bf0.w;
        acc[4] = bf1.x; acc[5] = bf1.y; acc[6] = bf1.z; acc[7] = bf1.w;
    }

    float sumvs = 0.0f;
    #pragma unroll 8
    for (int k = 0; k < K; ++k) {
        const float vs = vals[k];
        const uint2 q  = *(const uint2*)(Wq + ((long)idxs[k] << 10) + c8);
        sumvs += vs;
        acc[0] = fmaf(vs, (float)( q.x        & 0xffu), acc[0]);
        acc[1] = fmaf(vs, (float)((q.x >>  8) & 0xffu), acc[1]);
        acc[2] = fmaf(vs, (float)((q.x >> 16) & 0xffu), acc[2]);
        acc[3] = fmaf(vs, (float)( q.x >> 24        ), acc[3]);
        acc[4] = fmaf(vs, (float)( q.y        & 0xffu), acc[4]);
        acc[5] = fmaf(vs, (float)((q.y >>  8) & 0xffu), acc[5]);
        acc[6] = fmaf(vs, (float)((q.y >> 16) & 0xffu), acc[6]);
        acc[7] = fmaf(vs, (float)( q.y >> 24        ), acc[7]);
    }
    // remove the excess-128 bias in one fma per element
    #pragma unroll
    for (int j = 0; j < 8; ++j) acc[j] = fmaf(sumvs, -128.0f, acc[j]);

    {
        float* dst = (half == 0 ? s_wp : s_bp) + c8;
        #pragma unroll
        for (int j = 0; j < 8; ++j) dst[j] = acc[j];
    }
    __syncthreads();

    const float u   = us[b];
    const float th  = them[b];
    const int   idx = lsi[b];
    const float cc  = 127.0f / 128.0f;

    // ---- layer 1 ----
    float p[16];
    #pragma unroll
    for (int j = 0; j < 16; ++j) p[j] = 0.0f;

    const float* W1sel = W1 + idx * (L2C + 1);
    const int e0 = t * 4;
    #pragma unroll
    for (int q = 0; q < 4; ++q) {
        const int e = e0 + q;
        float l0p;
        if (e < 512) {
            const float a0 = clip01(u * s_wp[e]       + th * s_bp[e]);
            const float a1 = clip01(u * s_wp[e + 512] + th * s_bp[e + 512]);
            l0p = a0 * a1;
        } else {
            const int   c   = e - 512;
            const float b0  = clip01(u * s_bp[c] + th * s_wp[c]);
            const float b1v = clip01(u * s_bp[e] + th * s_wp[e]);
            l0p = b0 * b1v;
        }
        l0p *= cc;
        const float* wrow = W1sel + e * W1COLS;
        #pragma unroll
        for (int j = 0; j < 16; ++j) p[j] = fmaf(l0p, wrow[j], p[j]);
    }

    const int lane = t & 63;
    const int wid  = t >> 6;
    #pragma unroll
    for (int j = 0; j < 16; ++j) {
        float v = p[j];
        v += __shfl_down(v, 32);
        v += __shfl_down(v, 16);
        v += __shfl_down(v, 8);
        v += __shfl_down(v, 4);
        v += __shfl_down(v, 2);
        v += __shfl_down(v, 1);
        if (lane == 0) s_red[wid * 16 + j] = v;
    }
    __syncthreads();

    if (t < 16) {
        float x1 = s_red[t] + s_red[16 + t] + s_red[32 + t] + s_red[48 + t]
                 + b1[idx * (L2C + 1) + t];
        if (t == 15) {
            s_l1f = x1;
        } else {
            float cx = clip01(x1);
            s_v[t]       = cx * cx * cc;
            s_v[L2C + t] = cx * cc;
        }
    }
    __syncthreads();

    if (t < L3C) {
        float acc2 = b2[idx * L3C + t];
        #pragma unroll
        for (int r = 0; r < 2 * L2C; ++r)
            acc2 = fmaf(s_v[r], W2[r * W2COLS + idx * L3C + t], acc2);
        s_p2[t] = clip01(acc2) * W3[t * COUNT + idx];
    }
    __syncthreads();

    if (t == 0) {
        float s = 0.0f;
        #pragma unroll
        for (int m = 0; m < L3C; ++m) s += s_p2[m];
        out[b] = s + b3[idx] + s_l1f;
    }
}

// ---- fp32 single-kernel fallback (ws too small) — verified 186 us ----
__global__ __launch_bounds__(BDIM) void nnue_fused_f(
    const float* __restrict__ us,
    const float* __restrict__ them,
    const int*   __restrict__ wi,
    const float* __restrict__ wv,
    const int*   __restrict__ bi,
    const float* __restrict__ bvv,
    const int*   __restrict__ lsi,
    const float* __restrict__ W_ft,
    const float* __restrict__ b_ft,
    const float* __restrict__ W1,
    const float* __restrict__ b1,
    const float* __restrict__ W2,
    const float* __restrict__ b2,
    const float* __restrict__ W3,
    const float* __restrict__ b3,
    float* __restrict__ out)
{
    const int b = blockIdx.x;
    const int t = threadIdx.x;

    __shared__ int   s_idx[2 * K];
    __shared__ float s_val[2 * K];
    __shared__ float s_l0[2 * L1];
    __shared__ float s_red[4 * 16];
    __shared__ float s_v[2 * L2C];
    __shared__ float s_p2[L3C];
    __shared__ float s_l1f;

    if (t < K)          { s_idx[t] = wi[b * K + t];        s_val[t] = wv[b * K + t]; }
    else if (t < 2 * K) { s_idx[t] = bi[b * K + (t - K)];  s_val[t] = bvv[b * K + (t - K)]; }
    __syncthreads();

    const int c4 = t * 4;
    float4 accW = *(const float4*)(b_ft + c4);
    float4 accB = accW;

    #pragma unroll 8
    for (int k = 0; k < K; ++k) {
        const float  vwk = s_val[k];
        const float  vbk = s_val[K + k];
        const float4 rw  = *(const float4*)(W_ft + ((long)s_idx[k]     << 10) + c4);
        const float4 rb  = *(const float4*)(W_ft + ((long)s_idx[K + k] << 10) + c4);
        accW.x = fmaf(vwk, rw.x, accW.x);
        accW.y = fmaf(vwk, rw.y, accW.y);
        accW.z = fmaf(vwk, rw.z, accW.z);
        accW.w = fmaf(vwk, rw.w, accW.w);
        accB.x = fmaf(vbk, rb.x, accB.x);
        accB.y = fmaf(vbk, rb.y, accB.y);
        accB.z = fmaf(vbk, rb.z, accB.z);
        accB.w = fmaf(vbk, rb.w, accB.w);
    }

    const float u  = us[b];
    const float th = them[b];
    float4 A, Bv;
    A.x  = clip01(u * accW.x + th * accB.x);
    A.y  = clip01(u * accW.y + th * accB.y);
    A.z  = clip01(u * accW.z + th * accB.z);
    A.w  = clip01(u * accW.w + th * accB.w);
    Bv.x = clip01(u * accB.x + th * accW.x);
    Bv.y = clip01(u * accB.y + th * accW.y);
    Bv.z = clip01(u * accB.z + th * accW.z);
    Bv.w = clip01(u * accB.w + th * accW.w);
    *(float4*)(s_l0 + c4)      = A;
    *(float4*)(s_l0 + L1 + c4) = Bv;
    __syncthreads();

    const int   idx = lsi[b];
    const float cc  = 127.0f / 128.0f;

    float p[16];
    #pragma unroll
    for (int j = 0; j < 16; ++j) p[j] = 0.0f;

    const float* W1sel = W1 + idx * (L2C + 1);
    #pragma unroll
    for (int q = 0; q < 4; ++q) {
        const int e = c4 + q;
        float l0p;
        if (e < 512) l0p = s_l0[e] * s_l0[e + 512];
        else         l0p = s_l0[e + 512] * s_l0[e + 1024];
        l0p *= cc;
        const float* wrow = W1sel + e * W1COLS;
        #pragma unroll
        for (int j = 0; j < 16; ++j) p[j] = fmaf(l0p, wrow[j], p[j]);
    }

    const int lane = t & 63;
    const int wid  = t >> 6;
    #pragma unroll
    for (int j = 0; j < 16; ++j) {
        float v = p[j];
        v += __shfl_down(v, 32);
        v += __shfl_down(v, 16);
        v += __shfl_down(v, 8);
        v += __shfl_down(v, 4);
        v += __shfl_down(v, 2);
        v += __shfl_down(v, 1);
        if (lane == 0) s_red[wid * 16 + j] = v;
    }
    __syncthreads();

    if (t < 16) {
        float x1 = s_red[t] + s_red[16 + t] + s_red[32 + t] + s_red[48 + t]
                 + b1[idx * (L2C + 1) + t];
        if (t == 15) {
            s_l1f = x1;
        } else {
            float cx = clip01(x1);
            s_v[t]       = cx * cx * cc;
            s_v[L2C + t] = cx * cc;
        }
    }
    __syncthreads();

    if (t < L3C) {
        float acc = b2[idx * L3C + t];
        #pragma unroll
        for (int r = 0; r < 2 * L2C; ++r)
            acc = fmaf(s_v[r], W2[r * W2COLS + idx * L3C + t], acc);
        s_p2[t] = clip01(acc) * W3[t * COUNT + idx];
    }
    __syncthreads();

    if (t == 0) {
        float s = 0.0f;
        #pragma unroll
        for (int m = 0; m < L3C; ++m) s += s_p2[m];
        out[b] = s + b3[idx] + s_l1f;
    }
}

extern "C" void kernel_launch(void* const* d_in, const int* in_sizes, int n_in,
                              void* d_out, int out_size, void* d_ws, size_t ws_size,
                              hipStream_t stream) {
    const float* us   = (const float*)d_in[0];
    const float* them = (const float*)d_in[1];
    const int*   wi   = (const int*)  d_in[2];
    const float* wv   = (const float*)d_in[3];
    const int*   bi   = (const int*)  d_in[4];
    const float* bv   = (const float*)d_in[5];
    const int*   lsi  = (const int*)  d_in[6];
    const float* W_ft = (const float*)d_in[7];
    const float* b_ft = (const float*)d_in[8];
    const float* W1   = (const float*)d_in[9];
    const float* b1   = (const float*)d_in[10];
    const float* W2   = (const float*)d_in[11];
    const float* b2   = (const float*)d_in[12];
    const float* W3   = (const float*)d_in[13];
    const float* b3   = (const float*)d_in[14];
    float*       out  = (float*)d_out;

    const int Bn = in_sizes[0]; // 4096 batch rows
    const size_t qTableBytes = (size_t)NF * L1;                  // 23.1 MB
    const size_t needed      = qTableBytes + (size_t)NF * sizeof(float);

    if (ws_size >= needed) {
        unsigned char* Wq  = (unsigned char*)d_ws;
        float*         scl = (float*)((char*)d_ws + qTableBytes);
        quant_w_ft<<<(NF + 3) / 4, 256, 0, stream>>>(W_ft, Wq, scl, NF);
        nnue_fused_q<<<Bn, BDIM, 0, stream>>>(us, them, wi, wv, bi, bv, lsi,
                                              Wq, scl, b_ft, W1, b1, W2, b2, W3, b3, out);
    } else {
        nnue_fused_f<<<Bn, BDIM, 0, stream>>>(us, them, wi, wv, bi, bv, lsi,
                                              W_ft, b_ft, W1, b1, W2, b2, W3, b3, out);
    }
}